// Round 3
// baseline (103.217 us; speedup 1.0000x reference)
//
#include <hip/hip_runtime.h>

// ---------------------------------------------------------------------------
// SimpleAttention: out[b,h,w,d] = softmax_bhw( x^T (WqWk^T) x ) * (x . rowsum(Wv)) * Wo[d] + bo[d]
// prep(M=Wq@Wk^T split bf16 hi/lo) -> score GEMM (MFMA, 3-segment split
// precision, K-halved double-buffered staging, swizzled LDS, 8 waves) ->
// per-batch online softmax stats -> rank-1 output write.
// ---------------------------------------------------------------------------

typedef __bf16 bf16_t;
typedef __attribute__((ext_vector_type(8))) __bf16 bf16x8;
typedef __attribute__((ext_vector_type(4))) __bf16 bf16x4;
typedef __attribute__((ext_vector_type(4))) float f32x4;

#define NBATCH 16
#define NPIX   65536      // 16*64*64
#define PPB    4096       // pixels per batch (softmax group)

// ws byte offsets
#define MH_OFF    0u
#define ML_OFF    131072u
#define U_OFF     262144u
#define WV_OFF    263168u
#define SCL_OFF   264192u   // [0]=c0 (bq.bk), [1]=bvs (sum bv)
#define SCORE_OFF 264448u
#define SV_OFF    526592u
#define BMAX_OFF  788736u
#define BSUM_OFF  788800u

// ---------------------------------------------------------------------------
// prep: blocks 0..255 compute M[c][c'] = Wq[c,:].Wk[c',:], split to bf16 hi/lo.
// block 256 computes u = Wq@bk + Wk@bq, wv = rowsum(Wv), c0 = bq.bk, bvs = sum(bv).
// ---------------------------------------------------------------------------
__global__ __launch_bounds__(256) void prep_kernel(
    const float* __restrict__ Wq, const float* __restrict__ bq,
    const float* __restrict__ Wk, const float* __restrict__ bk,
    const float* __restrict__ Wv, const float* __restrict__ bv,
    bf16_t* __restrict__ Mh, bf16_t* __restrict__ Ml,
    float* __restrict__ u, float* __restrict__ wv, float* __restrict__ scl)
{
    const int t = threadIdx.x;
    if (blockIdx.x < 256) {
        const int c = blockIdx.x;
        __shared__ __align__(16) float wq_row[256];
        wq_row[t] = Wq[c * 256 + t];
        __syncthreads();
        const float4* wk4 = (const float4*)(Wk + t * 256);
        const float4* wq4 = (const float4*)wq_row;
        float acc = 0.f;
#pragma unroll 8
        for (int i = 0; i < 64; ++i) {
            float4 a = wq4[i], b = wk4[i];
            acc += a.x * b.x + a.y * b.y + a.z * b.z + a.w * b.w;
        }
        bf16_t h = (bf16_t)acc;
        float hf = (float)h;
        bf16_t l = (bf16_t)(acc - hf);
        Mh[c * 256 + t] = h;
        Ml[c * 256 + t] = l;
    } else {
        float uacc = 0.f, wvacc = 0.f;
        const float* wqr = Wq + t * 256;
        const float* wkr = Wk + t * 256;
        const float* wvr = Wv + t * 256;
#pragma unroll 4
        for (int d = 0; d < 256; ++d) {
            uacc += wqr[d] * bk[d] + wkr[d] * bq[d];
            wvacc += wvr[d];
        }
        u[t] = uacc;
        wv[t] = wvacc;
        __shared__ float r1[256], r2[256];
        r1[t] = bq[t] * bk[t];
        r2[t] = bv[t];
        __syncthreads();
        for (int s = 128; s > 0; s >>= 1) {
            if (t < s) { r1[t] += r1[t + s]; r2[t] += r2[t + s]; }
            __syncthreads();
        }
        if (t == 0) { scl[0] = r1[0]; scl[1] = r2[0]; }
    }
}

// ---------------------------------------------------------------------------
// score kernel v3: 64 pixels/block, 512 threads (8 waves), wave w owns cols
// [w*32, w*32+32) x all 64 rows. K staged in two halves (double-buffered in
// the two column-ranges of the same 64KB swizzled LDS tile); half-1 global
// loads issued before half-0's MFMA sweep. sv and u-dot folded into staging.
// ---------------------------------------------------------------------------
__device__ __forceinline__ int swz(int row, int col) {
    return row * 256 + (col ^ ((row & 7) << 3));
}

__global__ __launch_bounds__(512, 4) void score_kernel(
    const float* __restrict__ x,
    const bf16_t* __restrict__ Mh, const bf16_t* __restrict__ Ml,
    const float* __restrict__ u, const float* __restrict__ wvp,
    const float* __restrict__ scl,
    float* __restrict__ score, float* __restrict__ svout)
{
    __shared__ __align__(16) char smem[65536];
    __shared__ float svp[64], tpp[64];
    bf16_t* Ah = (bf16_t*)smem;            // [64][256] swizzled hi, 32KB
    bf16_t* Al = Ah + 16384;               // [64][256] swizzled lo, 32KB
    float* redS = (float*)smem;            // overlay after bar3: [8][64]

    const int t = threadIdx.x;
    const int lane = t & 63;
    const int wid = t >> 6;        // wave 0..7
    const int l15 = lane & 15;
    const int lg = lane >> 4;      // 0..3
    const int pix0 = blockIdx.x * 64;
    const int wcol0 = wid * 32;

    const int srow = t >> 3;       // staging row 0..63
    const int sch = (t & 7) * 16;  // channel base within K-half
    const float* xrow = x + (size_t)(pix0 + srow) * 256;

    float sv_acc = 0.f, tp_acc = 0.f;

#define CVT_WRITE_DOTS(XV, H)                                                 \
    {                                                                         \
        _Pragma("unroll")                                                     \
        for (int j = 0; j < 2; ++j) {                                         \
            bf16x8 hi, lo;                                                    \
            _Pragma("unroll")                                                 \
            for (int e = 0; e < 8; ++e) {                                     \
                float f = ((const float*)XV)[j * 8 + e];                      \
                bf16_t h = (bf16_t)f;                                         \
                hi[e] = h;                                                    \
                lo[e] = (bf16_t)(f - (float)h);                               \
            }                                                                 \
            int idx = swz(srow, (H) * 128 + sch + j * 8);                     \
            *(bf16x8*)&Ah[idx] = hi;                                          \
            *(bf16x8*)&Al[idx] = lo;                                          \
        }                                                                     \
        _Pragma("unroll")                                                     \
        for (int i = 0; i < 4; ++i) {                                         \
            float4 wvv = *(const float4*)(wvp + (H) * 128 + sch + i * 4);     \
            float4 uvv = *(const float4*)(u + (H) * 128 + sch + i * 4);       \
            sv_acc += XV[i].x * wvv.x + XV[i].y * wvv.y +                     \
                      XV[i].z * wvv.z + XV[i].w * wvv.w;                      \
            tp_acc += XV[i].x * uvv.x + XV[i].y * uvv.y +                     \
                      XV[i].z * uvv.z + XV[i].w * uvv.w;                      \
        }                                                                     \
    }

    f32x4 acc[4][2];
#pragma unroll
    for (int i = 0; i < 4; ++i)
#pragma unroll
        for (int j = 0; j < 2; ++j)
            acc[i][j] = (f32x4){0.f, 0.f, 0.f, 0.f};

#define MFMA_HALF(H)                                                          \
    _Pragma("unroll")                                                         \
    for (int ks = (H) * 4; ks < (H) * 4 + 4; ++ks) {                          \
        const int k0 = ks * 32;                                               \
        bf16x8 afh[4], afl[4];                                                \
        _Pragma("unroll")                                                     \
        for (int rf = 0; rf < 4; ++rf) {                                      \
            int idx = swz(rf * 16 + l15, k0 + lg * 8);                        \
            afh[rf] = *(const bf16x8*)&Ah[idx];                               \
            afl[rf] = *(const bf16x8*)&Al[idx];                               \
        }                                                                     \
        bf16x8 bfh[2], bfl[2];                                                \
        _Pragma("unroll")                                                     \
        for (int cf = 0; cf < 2; ++cf) {                                      \
            size_t bo = (size_t)(wcol0 + cf * 16 + l15) * 256 + k0 + lg * 8;  \
            bfh[cf] = *(const bf16x8*)(Mh + bo);                              \
            bfl[cf] = *(const bf16x8*)(Ml + bo);                              \
        }                                                                     \
        _Pragma("unroll")                                                     \
        for (int rf = 0; rf < 4; ++rf)                                        \
            _Pragma("unroll")                                                 \
            for (int cf = 0; cf < 2; ++cf) {                                  \
                acc[rf][cf] = __builtin_amdgcn_mfma_f32_16x16x32_bf16(        \
                    afh[rf], bfh[cf], acc[rf][cf], 0, 0, 0);                  \
                acc[rf][cf] = __builtin_amdgcn_mfma_f32_16x16x32_bf16(        \
                    afl[rf], bfh[cf], acc[rf][cf], 0, 0, 0);                  \
                acc[rf][cf] = __builtin_amdgcn_mfma_f32_16x16x32_bf16(        \
                    afh[rf], bfl[cf], acc[rf][cf], 0, 0, 0);                  \
            }                                                                 \
    }

    // ---- stage half 0 ----
    float4 xva[4];
#pragma unroll
    for (int i = 0; i < 4; ++i) xva[i] = *(const float4*)(xrow + sch + i * 4);
    CVT_WRITE_DOTS(xva, 0);

    // ---- issue half-1 loads early (in flight across bar1 + half-0 MFMAs) ----
    float4 xvb[4];
#pragma unroll
    for (int i = 0; i < 4; ++i) xvb[i] = *(const float4*)(xrow + 128 + sch + i * 4);

    __syncthreads();   // bar1: half-0 LDS tile ready
    MFMA_HALF(0);

    // ---- stage half 1 ----
    CVT_WRITE_DOTS(xvb, 1);
    // reduce sv/tp across the 8 lanes sharing this row, write once
#pragma unroll
    for (int m = 1; m < 8; m <<= 1) {
        sv_acc += __shfl_xor(sv_acc, m, 64);
        tp_acc += __shfl_xor(tp_acc, m, 64);
    }
    if ((lane & 7) == 0) { svp[srow] = sv_acc; tpp[srow] = tp_acc; }

    __syncthreads();   // bar2: half-1 LDS tile ready
    MFMA_HALF(1);

    // ---- epilogue: s_p(partial) = sum over this wave's 32 cols of x*Y ----
    float sacc[4][4];
#pragma unroll
    for (int rf = 0; rf < 4; ++rf) {
#pragma unroll
        for (int r = 0; r < 4; ++r) {
            int row = rf * 16 + lg * 4 + r;   // C layout: col=lane&15, row=(lane>>4)*4+reg
            float s = 0.f;
#pragma unroll
            for (int cf = 0; cf < 2; ++cf) {
                int idx = swz(row, wcol0 + cf * 16 + l15);
                float xv = (float)Ah[idx] + (float)Al[idx];
                s += xv * acc[rf][cf][r];
            }
#pragma unroll
            for (int m = 1; m < 16; m <<= 1) s += __shfl_xor(s, m, 64);
            sacc[rf][r] = s;
        }
    }
    __syncthreads();   // bar3: all LDS x-reads done; safe to overlay reductions
    if (l15 == 0) {
#pragma unroll
        for (int rf = 0; rf < 4; ++rf)
#pragma unroll
            for (int r = 0; r < 4; ++r)
                redS[wid * 64 + rf * 16 + lg * 4 + r] = sacc[rf][r];
    }
    __syncthreads();   // bar4
    if (t < 64) {
        float s = tpp[t] + scl[0];
#pragma unroll
        for (int w = 0; w < 8; ++w) s += redS[w * 64 + t];
        score[pix0 + t] = s;
        svout[pix0 + t] = svp[t] + scl[1];
    }
#undef CVT_WRITE_DOTS
#undef MFMA_HALF
}

// ---------------------------------------------------------------------------
// per-batch softmax stats: single pass, online (m, sum) with shfl combine
// ---------------------------------------------------------------------------
__global__ __launch_bounds__(256) void stats_kernel(
    const float* __restrict__ score,
    float* __restrict__ bmax, float* __restrict__ bsum)
{
    const int b = blockIdx.x, t = threadIdx.x;
    const int lane = t & 63, wid = t >> 6;
    const float4* s4 = (const float4*)(score + b * PPB);
    float4 v[4];
#pragma unroll
    for (int i = 0; i < 4; ++i) v[i] = s4[t + i * 256];
    float m = v[0].x;
#pragma unroll
    for (int i = 0; i < 4; ++i) {
        m = fmaxf(m, fmaxf(fmaxf(v[i].x, v[i].y), fmaxf(v[i].z, v[i].w)));
    }
    float sum = 0.f;
#pragma unroll
    for (int i = 0; i < 4; ++i) {
        sum += __expf(v[i].x - m) + __expf(v[i].y - m) +
               __expf(v[i].z - m) + __expf(v[i].w - m);
    }
#pragma unroll
    for (int k = 1; k < 64; k <<= 1) {
        float om = __shfl_xor(m, k, 64);
        float os = __shfl_xor(sum, k, 64);
        float nm = fmaxf(m, om);
        sum = sum * __expf(m - nm) + os * __expf(om - nm);
        m = nm;
    }
    __shared__ float sm[4], ss[4];
    if (lane == 0) { sm[wid] = m; ss[wid] = sum; }
    __syncthreads();
    if (t == 0) {
        float M = fmaxf(fmaxf(sm[0], sm[1]), fmaxf(sm[2], sm[3]));
        float S = ss[0] * __expf(sm[0] - M) + ss[1] * __expf(sm[1] - M) +
                  ss[2] * __expf(sm[2] - M) + ss[3] * __expf(sm[3] - M);
        bmax[b] = M; bsum[b] = S;
    }
}

// ---------------------------------------------------------------------------
// output: out[p, 0:256] = g_p * Wo + bo,  g_p = softmax(score)_p * sv_p
// ---------------------------------------------------------------------------
__global__ __launch_bounds__(256) void out_kernel(
    const float* __restrict__ score, const float* __restrict__ sv,
    const float* __restrict__ bmax, const float* __restrict__ bsum,
    const float* __restrict__ Wo, const float* __restrict__ bo,
    float* __restrict__ out)
{
    const int total = NPIX * 64;  // float4 count
    const int stride = gridDim.x * blockDim.x;
    for (int idx = blockIdx.x * blockDim.x + threadIdx.x; idx < total; idx += stride) {
        int p = idx >> 6;
        int c4 = (idx & 63) << 2;
        int b = p >> 12;
        float g = __expf(score[p] - bmax[b]) / bsum[b] * sv[p];
        float4 w = *(const float4*)(Wo + c4);
        float4 bb = *(const float4*)(bo + c4);
        float4 o = { g * w.x + bb.x, g * w.y + bb.y, g * w.z + bb.z, g * w.w + bb.w };
        *(float4*)(out + (size_t)p * 256 + c4) = o;
    }
}

extern "C" void kernel_launch(void* const* d_in, const int* in_sizes, int n_in,
                              void* d_out, int out_size, void* d_ws, size_t ws_size,
                              hipStream_t stream) {
    const float* x  = (const float*)d_in[0];
    const float* Wq = (const float*)d_in[1];
    const float* bq = (const float*)d_in[2];
    const float* Wk = (const float*)d_in[3];
    const float* bk = (const float*)d_in[4];
    const float* Wv = (const float*)d_in[5];
    const float* bv = (const float*)d_in[6];
    const float* Wo = (const float*)d_in[7];
    const float* bo = (const float*)d_in[8];
    float* out = (float*)d_out;
    char* ws = (char*)d_ws;

    bf16_t* Mh = (bf16_t*)(ws + MH_OFF);
    bf16_t* Ml = (bf16_t*)(ws + ML_OFF);
    float* u   = (float*)(ws + U_OFF);
    float* wv  = (float*)(ws + WV_OFF);
    float* scl = (float*)(ws + SCL_OFF);
    float* score = (float*)(ws + SCORE_OFF);
    float* sv    = (float*)(ws + SV_OFF);
    float* bmax  = (float*)(ws + BMAX_OFF);
    float* bsum  = (float*)(ws + BSUM_OFF);

    prep_kernel<<<dim3(257), dim3(256), 0, stream>>>(Wq, bq, Wk, bk, Wv, bv, Mh, Ml, u, wv, scl);
    score_kernel<<<dim3(NPIX / 64), dim3(512), 0, stream>>>(x, Mh, Ml, u, wv, scl, score, sv);
    stats_kernel<<<dim3(NBATCH), dim3(256), 0, stream>>>(score, bmax, bsum);
    out_kernel<<<dim3(4096), dim3(256), 0, stream>>>(score, sv, bmax, bsum, Wo, bo, out);
}